// Round 1
// baseline (813.304 us; speedup 1.0000x reference)
//
#include <hip/hip_runtime.h>

// ChunkedCrossAttention on MI355X (gfx950).
// Pipeline: cast(fp32->bf16) -> [Q,K,V] bf16 MFMA GEMMs -> RoPE -> fused
// attention per (chunk,head) -> output GEMM (bias + row-shift epilogue).
// Workspace layout (bytes): see kernel_launch. Requires ~340 MB of d_ws.

#define DEV __device__ __forceinline__

typedef __bf16 bf16x8 __attribute__((ext_vector_type(8)));
typedef float f32x4 __attribute__((ext_vector_type(4)));

DEV unsigned short f2bf(float f) {
  union { float f; unsigned int u; } v; v.f = f;
  unsigned int u = v.u;
  unsigned int r = (u + 0x7FFFu + ((u >> 16) & 1u)) >> 16;  // RNE
  return (unsigned short)r;
}
DEV float bf2f(unsigned short h) {
  union { unsigned int u; float f; } v; v.u = ((unsigned int)h) << 16;
  return v.f;
}

// async global->LDS, 16B per lane; LDS dest = uniform base + lane*16
DEV void ldst16(const void* g, void* l) {
  __builtin_amdgcn_global_load_lds(
      (const __attribute__((address_space(1))) void*)g,
      (__attribute__((address_space(3))) void*)l, 16, 0, 0);
}

// ---------------------------------------------------------------------------
// Elementwise / prep kernels
// ---------------------------------------------------------------------------

// ctx fp32 -> bf16 straight cast. 8 elems/thread, exact coverage.
__global__ __launch_bounds__(256) void cast_ctx_k(const float* __restrict__ src,
                                                  unsigned short* __restrict__ dst) {
  size_t i = ((size_t)blockIdx.x * 256 + threadIdx.x) * 8;
  float4 a = *(const float4*)(src + i);
  float4 b = *(const float4*)(src + i + 4);
  union { uint4 v; unsigned short s[8]; } u;
  u.s[0] = f2bf(a.x); u.s[1] = f2bf(a.y); u.s[2] = f2bf(a.z); u.s[3] = f2bf(a.w);
  u.s[4] = f2bf(b.x); u.s[5] = f2bf(b.y); u.s[6] = f2bf(b.z); u.s[7] = f2bf(b.w);
  *(uint4*)(dst + i) = u.v;
}

// xs[m] = x[b, p+63] (p<=4032) else 0;  m = b*4096+p. Output bf16 (16384x1024).
__global__ __launch_bounds__(256) void cast_x_k(const float* __restrict__ x,
                                                unsigned short* __restrict__ xq) {
  size_t flat = ((size_t)blockIdx.x * 256 + threadIdx.x) * 8;
  int row = (int)(flat >> 10);
  int c = (int)(flat & 1023);
  int b = row >> 12, p = row & 4095;
  union { uint4 v; unsigned short s[8]; } u;
  if (p <= 4032) {
    const float* sp = x + (((size_t)(b << 12) + p + 63) << 10) + c;
    float4 a = *(const float4*)sp;
    float4 d = *(const float4*)(sp + 4);
    u.s[0] = f2bf(a.x); u.s[1] = f2bf(a.y); u.s[2] = f2bf(a.z); u.s[3] = f2bf(a.w);
    u.s[4] = f2bf(d.x); u.s[5] = f2bf(d.y); u.s[6] = f2bf(d.z); u.s[7] = f2bf(d.w);
  } else {
    #pragma unroll
    for (int e = 0; e < 8; ++e) u.s[e] = 0;
  }
  *(uint4*)(xq + flat) = u.v;
}

// W (K x N, n-contig) -> Wt (N x K, k-contig) bf16, with optional scale.
__global__ __launch_bounds__(256) void transpose_w_k(const float* __restrict__ W,
                                                     unsigned short* __restrict__ Wt,
                                                     int kbits, int N, float scale) {
  int idx = blockIdx.x * 256 + threadIdx.x;
  int K = 1 << kbits;
  int k = idx & (K - 1), n = idx >> kbits;
  Wt[idx] = f2bf(W[(size_t)k * N + n] * scale);
}

// cos/sin tables: k tables 128x64; q tables (row 63 of q_pos_emb) 64.
__global__ __launch_bounds__(256) void rope_tables_k(const float* __restrict__ qpe,
                                                     const float* __restrict__ kpe,
                                                     float* __restrict__ ck, float* __restrict__ sk,
                                                     float* __restrict__ cq, float* __restrict__ sq) {
  int t = blockIdx.x * 256 + threadIdx.x;  // 0..8191
  float f = kpe[t];
  ck[t] = cosf(f);
  sk[t] = sinf(f);
  if (t < 64) {
    float g = qpe[63 * 64 + t];
    cq[t] = cosf(g);
    sq[t] = sinf(g);
  }
}

// RoPE on K in place. k layout (bc*256+j, h*64+d). freqs index j%128.
__global__ __launch_bounds__(256) void rope_k_k(unsigned short* __restrict__ kb,
                                                const float* __restrict__ ck,
                                                const float* __restrict__ sk) {
  size_t t = (size_t)blockIdx.x * 256 + threadIdx.x;  // 16,777,216
  int m = (int)(t >> 8);
  int rest = (int)(t & 255);
  int h = rest >> 5, dp = rest & 31;
  size_t base = (size_t)m * 512 + h * 64;
  int fi = (m & 127) * 64 + dp;
  float v0 = bf2f(kb[base + dp]);
  float v1 = bf2f(kb[base + dp + 32]);
  float c0 = ck[fi], s0 = sk[fi], c1 = ck[fi + 32], s1 = sk[fi + 32];
  kb[base + dp] = f2bf(v0 * c0 - v1 * s0);
  kb[base + dp + 32] = f2bf(v1 * c1 + v0 * s1);
}

// RoPE on Q: only row i=0 of each 64-row chunk (qpe rows 1..63 are zero).
__global__ __launch_bounds__(256) void rope_q_k(unsigned short* __restrict__ qb,
                                                const float* __restrict__ cq,
                                                const float* __restrict__ sq) {
  int t = blockIdx.x * 256 + threadIdx.x;  // 65536
  int bc = t >> 8, rest = t & 255, h = rest >> 5, dp = rest & 31;
  size_t base = (size_t)(bc * 64) * 512 + h * 64;
  float v0 = bf2f(qb[base + dp]);
  float v1 = bf2f(qb[base + dp + 32]);
  qb[base + dp] = f2bf(v0 * cq[dp] - v1 * sq[dp]);
  qb[base + dp + 32] = f2bf(v1 * cq[dp + 32] + v0 * sq[dp + 32]);
}

// zero out rows 0..62 of each batch in d_out. One block per row.
__global__ __launch_bounds__(256) void zero_rows_k(float* __restrict__ out) {
  int b = blockIdx.x / 63, rr = blockIdx.x % 63;
  float4 z = {0.f, 0.f, 0.f, 0.f};
  *(float4*)(out + (((size_t)(b * 4096 + rr)) << 10) + threadIdx.x * 4) = z;
}

// ---------------------------------------------------------------------------
// GEMM: C(MxN) = A(MxK) * B^T(NxK), all bf16, fp32 accum, bf16 out.
// 128x128x64 tile, 256 threads (4 waves, 2x2 of 64x64), 16x16x32 MFMA.
// LDS rows are 8 chunks of 16B, chunk index XOR-swizzled with (row&7) so
// fragment ds_read_b128 is <=2-way bank conflicted (free, m136).
// blockIdx.z selects (B0,C0)/(B1,C1) to fuse K+V projections over one A.
// ---------------------------------------------------------------------------
__global__ __launch_bounds__(256) void gemm_bt(const unsigned short* __restrict__ A,
                                               const unsigned short* __restrict__ B0,
                                               const unsigned short* __restrict__ B1,
                                               unsigned short* __restrict__ C0,
                                               unsigned short* __restrict__ C1,
                                               int M, int N, int K) {
  __shared__ unsigned short As[128 * 64];
  __shared__ unsigned short Bs[128 * 64];
  const unsigned short* B = blockIdx.z ? B1 : B0;
  unsigned short* C = blockIdx.z ? C1 : C0;
  int m0 = blockIdx.x * 128, n0 = blockIdx.y * 128;
  int tid = threadIdx.x, w = tid >> 6, lane = tid & 63;
  int wm = (w & 1) * 64, wn = (w >> 1) * 64;
  int Lrow = lane >> 3, Lc = lane & 7;
  int srcC = Lc ^ (Lrow & 7);

  f32x4 acc[4][4] = {};

  for (int k0 = 0; k0 < K; k0 += 64) {
    #pragma unroll
    for (int q = 0; q < 4; ++q) {
      int t = w * 4 + q;
      ldst16(A + (size_t)(m0 + t * 8 + Lrow) * K + (k0 + srcC * 8), (char*)As + t * 1024);
      ldst16(B + (size_t)(n0 + t * 8 + Lrow) * K + (k0 + srcC * 8), (char*)Bs + t * 1024);
    }
    __syncthreads();
    #pragma unroll
    for (int k32 = 0; k32 < 2; ++k32) {
      int c = k32 * 4 + (lane >> 4);
      bf16x8 af[4], bfr[4];
      #pragma unroll
      for (int mt = 0; mt < 4; ++mt) {
        int m = wm + mt * 16 + (lane & 15);
        af[mt] = *(const bf16x8*)((const char*)As + m * 128 + (c ^ (m & 7)) * 16);
      }
      #pragma unroll
      for (int nt = 0; nt < 4; ++nt) {
        int n = wn + nt * 16 + (lane & 15);
        bfr[nt] = *(const bf16x8*)((const char*)Bs + n * 128 + (c ^ (n & 7)) * 16);
      }
      #pragma unroll
      for (int mt = 0; mt < 4; ++mt)
        #pragma unroll
        for (int nt = 0; nt < 4; ++nt)
          acc[mt][nt] = __builtin_amdgcn_mfma_f32_16x16x32_bf16(af[mt], bfr[nt], acc[mt][nt], 0, 0, 0);
    }
    __syncthreads();
  }
  // epilogue: C/D layout col=lane&15, row=(lane>>4)*4+reg (m89/m91 verified)
  #pragma unroll
  for (int mt = 0; mt < 4; ++mt)
    #pragma unroll
    for (int nt = 0; nt < 4; ++nt)
      #pragma unroll
      for (int r = 0; r < 4; ++r) {
        int m = m0 + wm + mt * 16 + (lane >> 4) * 4 + r;
        int n = n0 + wn + nt * 16 + (lane & 15);
        C[(size_t)m * N + n] = f2bf(acc[mt][nt][r]);
      }
}

// Output GEMM: out fp32 = A(16384x512) * Wo^T(1024x512) + bias, with the
// reference's row shift: out[b, t+63] = row(b*4096+t) for t<=4032.
__global__ __launch_bounds__(256) void gemm_out(const unsigned short* __restrict__ A,
                                                const unsigned short* __restrict__ B,
                                                const float* __restrict__ bias,
                                                float* __restrict__ out,
                                                int M, int N, int K) {
  __shared__ unsigned short As[128 * 64];
  __shared__ unsigned short Bs[128 * 64];
  int m0 = blockIdx.x * 128, n0 = blockIdx.y * 128;
  int tid = threadIdx.x, w = tid >> 6, lane = tid & 63;
  int wm = (w & 1) * 64, wn = (w >> 1) * 64;
  int Lrow = lane >> 3, Lc = lane & 7;
  int srcC = Lc ^ (Lrow & 7);

  f32x4 acc[4][4] = {};

  for (int k0 = 0; k0 < K; k0 += 64) {
    #pragma unroll
    for (int q = 0; q < 4; ++q) {
      int t = w * 4 + q;
      ldst16(A + (size_t)(m0 + t * 8 + Lrow) * K + (k0 + srcC * 8), (char*)As + t * 1024);
      ldst16(B + (size_t)(n0 + t * 8 + Lrow) * K + (k0 + srcC * 8), (char*)Bs + t * 1024);
    }
    __syncthreads();
    #pragma unroll
    for (int k32 = 0; k32 < 2; ++k32) {
      int c = k32 * 4 + (lane >> 4);
      bf16x8 af[4], bfr[4];
      #pragma unroll
      for (int mt = 0; mt < 4; ++mt) {
        int m = wm + mt * 16 + (lane & 15);
        af[mt] = *(const bf16x8*)((const char*)As + m * 128 + (c ^ (m & 7)) * 16);
      }
      #pragma unroll
      for (int nt = 0; nt < 4; ++nt) {
        int n = wn + nt * 16 + (lane & 15);
        bfr[nt] = *(const bf16x8*)((const char*)Bs + n * 128 + (c ^ (n & 7)) * 16);
      }
      #pragma unroll
      for (int mt = 0; mt < 4; ++mt)
        #pragma unroll
        for (int nt = 0; nt < 4; ++nt)
          acc[mt][nt] = __builtin_amdgcn_mfma_f32_16x16x32_bf16(af[mt], bfr[nt], acc[mt][nt], 0, 0, 0);
    }
    __syncthreads();
  }
  #pragma unroll
  for (int mt = 0; mt < 4; ++mt)
    #pragma unroll
    for (int nt = 0; nt < 4; ++nt)
      #pragma unroll
      for (int r = 0; r < 4; ++r) {
        int m = m0 + wm + mt * 16 + (lane >> 4) * 4 + r;
        int n = n0 + wn + nt * 16 + (lane & 15);
        int b = m >> 12, t = m & 4095;
        if (t <= 4032)
          out[((size_t)((b << 12) + t + 63)) * N + n] = acc[mt][nt][r] + bias[n];
      }
}

// ---------------------------------------------------------------------------
// Fused attention per (bc, h): sim = q k^T (MFMA), softmax w/ null key (fp32,
// register + shuffle), P -> LDS (bf16), v -> v^T via LDS, o = P v (MFMA),
// null_v added in fp32 epilogue, normalize by row sum, write bf16.
// ---------------------------------------------------------------------------
__global__ __launch_bounds__(256) void attn_kernel(const unsigned short* __restrict__ qb,
                                                   const unsigned short* __restrict__ kb,
                                                   const unsigned short* __restrict__ vb,
                                                   const float* __restrict__ nullk,
                                                   const float* __restrict__ nullv,
                                                   unsigned short* __restrict__ ob) {
  __shared__ unsigned short qs[64 * 64];    // 8 KB  [i][d], swizzled rows of 128B
  __shared__ unsigned short ks[256 * 64];   // 32 KB [j][d]; later reused as vt[d][j]
  __shared__ unsigned short ps[64 * 256];   // 32 KB [i][j], swizzled rows of 512B
  __shared__ float rnull[64];               // null sim, then exp(null - max)
  __shared__ float rsum[64];
  int bc = blockIdx.x, h = blockIdx.y;
  int tid = threadIdx.x, w = tid >> 6, lane = tid & 63;
  int Lrow = lane >> 3, Lc = lane & 7, srcC = Lc ^ (Lrow & 7);

  #pragma unroll
  for (int q8 = 0; q8 < 2; ++q8) {
    int t = w * 2 + q8;
    ldst16(qb + (size_t)(bc * 64 + t * 8 + Lrow) * 512 + h * 64 + srcC * 8, (char*)qs + t * 1024);
  }
  #pragma unroll
  for (int q8 = 0; q8 < 8; ++q8) {
    int t = w * 8 + q8;
    ldst16(kb + (size_t)(bc * 256 + t * 8 + Lrow) * 512 + h * 64 + srcC * 8, (char*)ks + t * 1024);
  }
  __syncthreads();

  // null-key sims: 4 lanes per row, 16 d each, combine via shuffles.
  {
    int rl = lane >> 2, part = lane & 3;
    int row = w * 16 + rl;
    float s = 0.f;
    #pragma unroll
    for (int e = 0; e < 16; ++e) {
      int d = part * 16 + e;
      unsigned short qv = *(const unsigned short*)((const char*)qs + row * 128 +
                                                   (((d >> 3) ^ (row & 7)) * 16) + (d & 7) * 2);
      s += bf2f(qv) * nullk[h * 64 + d];
    }
    s += __shfl_xor(s, 1);
    s += __shfl_xor(s, 2);
    if (part == 0) rnull[row] = s;
  }

  // sim: wave w owns rows [16w,16w+16), 16 n-tiles of 16 keys.
  f32x4 acc[16] = {};
  #pragma unroll
  for (int k32 = 0; k32 < 2; ++k32) {
    int c = k32 * 4 + (lane >> 4);
    int m = w * 16 + (lane & 15);
    bf16x8 a = *(const bf16x8*)((const char*)qs + m * 128 + (c ^ (m & 7)) * 16);
    #pragma unroll
    for (int nt = 0; nt < 16; ++nt) {
      int n = nt * 16 + (lane & 15);
      bf16x8 b = *(const bf16x8*)((const char*)ks + n * 128 + (c ^ (n & 7)) * 16);
      acc[nt] = __builtin_amdgcn_mfma_f32_16x16x32_bf16(a, b, acc[nt], 0, 0, 0);
    }
  }

  // softmax (unnormalized) per row; rows live across 16-lane groups.
  int g = lane >> 4;
  #pragma unroll
  for (int r = 0; r < 4; ++r) {
    int row = w * 16 + g * 4 + r;
    float mx = -3.0e38f;
    #pragma unroll
    for (int nt = 0; nt < 16; ++nt) mx = fmaxf(mx, acc[nt][r]);
    mx = fmaxf(mx, __shfl_xor(mx, 1));
    mx = fmaxf(mx, __shfl_xor(mx, 2));
    mx = fmaxf(mx, __shfl_xor(mx, 4));
    mx = fmaxf(mx, __shfl_xor(mx, 8));
    float ns = rnull[row];
    float mm = fmaxf(mx, ns);
    float s = 0.f;
    #pragma unroll
    for (int nt = 0; nt < 16; ++nt) {
      float p = __expf(acc[nt][r] - mm);
      acc[nt][r] = p;
      s += p;
    }
    s += __shfl_xor(s, 1);
    s += __shfl_xor(s, 2);
    s += __shfl_xor(s, 4);
    s += __shfl_xor(s, 8);
    float en = __expf(ns - mm);
    s += en;
    if ((lane & 15) == 0) {
      rsum[row] = s;
      rnull[row] = en;
    }
  }

  // P -> LDS bf16 (A-operand layout for PV).
  #pragma unroll
  for (int nt = 0; nt < 16; ++nt)
    #pragma unroll
    for (int r = 0; r < 4; ++r) {
      int row = w * 16 + g * 4 + r;
      int col = nt * 16 + (lane & 15);
      *(unsigned short*)((char*)ps + row * 512 + (((col >> 3) ^ (row & 7)) * 16) + (col & 7) * 2) =
          f2bf(acc[nt][r]);
    }
  __syncthreads();  // all waves done reading ks

  // v^T into ks area: thread t owns source row j=t.
  {
    unsigned short* vt = ks;
    const unsigned short* vg = vb + (size_t)(bc * 256 + tid) * 512 + h * 64;
    #pragma unroll
    for (int cc = 0; cc < 8; ++cc) {
      uint4 raw = *(const uint4*)(vg + cc * 8);
      union { uint4 v; unsigned short s[8]; } u;
      u.v = raw;
      #pragma unroll
      for (int e = 0; e < 8; ++e) {
        int d = cc * 8 + e;
        *(unsigned short*)((char*)vt + d * 512 + (((tid >> 3) ^ (d & 7)) * 16) + (tid & 7) * 2) = u.s[e];
      }
    }
  }
  __syncthreads();

  // o = P v : k over 256 keys, 4 n-tiles of d.
  f32x4 oacc[4] = {};
  #pragma unroll
  for (int k32 = 0; k32 < 8; ++k32) {
    int c = k32 * 4 + (lane >> 4);
    int m = w * 16 + (lane & 15);
    bf16x8 a = *(const bf16x8*)((const char*)ps + m * 512 + (c ^ (m & 7)) * 16);
    #pragma unroll
    for (int nt = 0; nt < 4; ++nt) {
      int n = nt * 16 + (lane & 15);
      bf16x8 b = *(const bf16x8*)((const char*)ks + n * 512 + (c ^ (n & 7)) * 16);
      oacc[nt] = __builtin_amdgcn_mfma_f32_16x16x32_bf16(a, b, oacc[nt], 0, 0, 0);
    }
  }
  #pragma unroll
  for (int nt = 0; nt < 4; ++nt)
    #pragma unroll
    for (int r = 0; r < 4; ++r) {
      int row = w * 16 + g * 4 + r;
      int d = nt * 16 + (lane & 15);
      float o = oacc[nt][r] + rnull[row] * nullv[h * 64 + d];
      o /= rsum[row];
      ob[((size_t)(bc * 64 + row) * 8 + h) * 64 + d] = f2bf(o);
    }
}

// ---------------------------------------------------------------------------
extern "C" void kernel_launch(void* const* d_in, const int* in_sizes, int n_in,
                              void* d_out, int out_size, void* d_ws, size_t ws_size,
                              hipStream_t stream) {
  const float* x = (const float*)d_in[0];
  const float* ctx = (const float*)d_in[1];
  const float* qpe = (const float*)d_in[2];
  const float* kpe = (const float*)d_in[3];
  const float* Wq = (const float*)d_in[4];
  const float* Wk = (const float*)d_in[5];
  const float* Wv = (const float*)d_in[6];
  const float* Wo = (const float*)d_in[7];
  const float* bo = (const float*)d_in[8];
  const float* nk = (const float*)d_in[9];
  const float* nv = (const float*)d_in[10];
  float* out = (float*)d_out;
  char* ws = (char*)d_ws;

  // workspace layout (bytes) — total ~339.8 MB
  unsigned short* xq   = (unsigned short*)(ws + 0);           // 33,554,432
  unsigned short* ctxb = (unsigned short*)(ws + 33554432);    // 134,217,728
  unsigned short* Wqt  = (unsigned short*)(ws + 167772160);   // 1,048,576
  unsigned short* Wkt  = (unsigned short*)(ws + 168820736);   // 1,048,576
  unsigned short* Wvt  = (unsigned short*)(ws + 169869312);   // 1,048,576
  unsigned short* Wot  = (unsigned short*)(ws + 170917888);   // 1,048,576
  unsigned short* qb   = (unsigned short*)(ws + 171966464);   // 16,777,216
  unsigned short* kb   = (unsigned short*)(ws + 188743680);   // 67,108,864
  unsigned short* vb   = (unsigned short*)(ws + 255852544);   // 67,108,864
  unsigned short* obuf = (unsigned short*)(ws + 322961408);   // 16,777,216
  float* cosk = (float*)(ws + 339738624);                     // 32,768
  float* sink = (float*)(ws + 339771392);                     // 32,768
  float* cosq = (float*)(ws + 339804160);                     // 256
  float* sinq = (float*)(ws + 339804416);                     // 256

  zero_rows_k<<<252, 256, 0, stream>>>(out);
  cast_ctx_k<<<32768, 256, 0, stream>>>(ctx, ctxb);
  cast_x_k<<<8192, 256, 0, stream>>>(x, xq);
  transpose_w_k<<<2048, 256, 0, stream>>>(Wq, Wqt, 10, 512, 0.125f);  // fold SCALE
  transpose_w_k<<<2048, 256, 0, stream>>>(Wk, Wkt, 10, 512, 1.0f);
  transpose_w_k<<<2048, 256, 0, stream>>>(Wv, Wvt, 10, 512, 1.0f);
  transpose_w_k<<<2048, 256, 0, stream>>>(Wo, Wot, 9, 1024, 1.0f);
  rope_tables_k<<<32, 256, 0, stream>>>(qpe, kpe, cosk, sink, cosq, sinq);

  // Q projection: (16384x1024)@(1024x512)
  gemm_bt<<<dim3(128, 4, 1), 256, 0, stream>>>(xq, Wqt, Wqt, qb, qb, 16384, 512, 1024);
  // K and V projections fused over z: (65536x1024)@(1024x512) x2
  gemm_bt<<<dim3(512, 4, 2), 256, 0, stream>>>(ctxb, Wkt, Wvt, kb, vb, 65536, 512, 1024);

  rope_q_k<<<256, 256, 0, stream>>>(qb, cosq, sinq);
  rope_k_k<<<65536, 256, 0, stream>>>(kb, cosk, sink);

  attn_kernel<<<dim3(256, 8), 256, 0, stream>>>(qb, kb, vb, nk, nv, obuf);

  // Output: (16384x512)@(512x1024) + bias, shifted rows
  gemm_out<<<dim3(128, 8), 256, 0, stream>>>(obuf, Wot, bo, out, 16384, 1024, 512);
}

// Round 2
// 804.533 us; speedup vs baseline: 1.0109x; 1.0109x over previous
//
#include <hip/hip_runtime.h>

// ChunkedCrossAttention on MI355X (gfx950) — round 2.
// Changes vs round 1:
//  - All GEMMs use 1-D grids with sibling-consecutive ordering (blocks sharing
//    an A panel dispatch back-to-back -> A re-reads hit L3, HBM reads ~once).
//  - RoPE-K fused into KV GEMM epilogue (on fp32 acc, pre-bf16-round).
//  - RoPE-Q fused into Q GEMM epilogue (only row i==0 of each 64-chunk).
//  - V written pre-transposed (LDS transpose in epilogue) as vtg[n][m];
//    attn stages V^T via global_load_lds instead of 64 scalar ds_writes/thread.
//  - 14 launches -> 6 (prep, cast, gemmQ, gemmKV, attn, gemmOut).

#define DEV __device__ __forceinline__

typedef __bf16 bf16x8 __attribute__((ext_vector_type(8)));
typedef float f32x4 __attribute__((ext_vector_type(4)));

DEV unsigned short f2bf(float f) {
  union { float f; unsigned int u; } v; v.f = f;
  unsigned int u = v.u;
  unsigned int r = (u + 0x7FFFu + ((u >> 16) & 1u)) >> 16;  // RNE
  return (unsigned short)r;
}
DEV float bf2f(unsigned short h) {
  union { unsigned int u; float f; } v; v.u = ((unsigned int)h) << 16;
  return v.f;
}

// async global->LDS, 16B per lane; LDS dest = uniform base + lane*16
DEV void ldst16(const void* g, void* l) {
  __builtin_amdgcn_global_load_lds(
      (const __attribute__((address_space(1))) void*)g,
      (__attribute__((address_space(3))) void*)l, 16, 0, 0);
}

// ---------------------------------------------------------------------------
// prep: weight transpose+cast (+SCALE fold), zero rows 0..62 per batch of out,
// rope cos/sin tables. One launch.
// ---------------------------------------------------------------------------
__global__ __launch_bounds__(256) void prep_k(const float* __restrict__ Wq,
                                              const float* __restrict__ Wk,
                                              const float* __restrict__ Wv,
                                              const float* __restrict__ Wo,
                                              const float* __restrict__ qpe,
                                              const float* __restrict__ kpe,
                                              unsigned short* __restrict__ Wqt,
                                              unsigned short* __restrict__ Wkt,
                                              unsigned short* __restrict__ Wvt,
                                              unsigned short* __restrict__ Wot,
                                              float* __restrict__ ck, float* __restrict__ sk,
                                              float* __restrict__ cq, float* __restrict__ sq,
                                              float* __restrict__ out) {
  int blk = blockIdx.x;
  if (blk < 8192) {
    int idx = blk * 256 + threadIdx.x;     // 0..2097151
    int which = idx >> 19;                 // 0..3
    int loc = idx & 524287;
    if (which < 3) {                       // Wq/Wk/Wv: (1024x512) -> (512x1024)
      int k = loc & 1023, n = loc >> 10;
      const float* W = which == 0 ? Wq : (which == 1 ? Wk : Wv);
      unsigned short* Wt = which == 0 ? Wqt : (which == 1 ? Wkt : Wvt);
      float scale = which == 0 ? 0.125f : 1.0f;
      Wt[loc] = f2bf(W[(size_t)k * 512 + n] * scale);
    } else {                               // Wo: (512x1024) -> (1024x512)
      int k = loc & 511, n = loc >> 9;
      Wot[loc] = f2bf(Wo[(size_t)k * 1024 + n]);
    }
  } else if (blk < 8444) {                 // zero rows 0..62 of each batch
    int r = blk - 8192;
    int b = r / 63, rr = r % 63;
    float4 z = {0.f, 0.f, 0.f, 0.f};
    *(float4*)(out + (((size_t)(b * 4096 + rr)) << 10) + threadIdx.x * 4) = z;
  } else {                                 // rope tables
    int t = (blk - 8444) * 256 + threadIdx.x;  // 0..8191
    float f = kpe[t];
    ck[t] = cosf(f);
    sk[t] = sinf(f);
    if (t < 64) {
      float g = qpe[63 * 64 + t];
      cq[t] = cosf(g);
      sq[t] = sinf(g);
    }
  }
}

// ---------------------------------------------------------------------------
// cast: ctx fp32->bf16, and x shifted+cast (xs[b,p]=x[b,p+63], p<=4032 else 0)
// ---------------------------------------------------------------------------
__global__ __launch_bounds__(256) void cast_k(const float* __restrict__ ctx,
                                              const float* __restrict__ x,
                                              unsigned short* __restrict__ ctxb,
                                              unsigned short* __restrict__ xq) {
  int blk = blockIdx.x;
  if (blk < 32768) {
    size_t i = ((size_t)blk * 256 + threadIdx.x) * 8;
    float4 a = *(const float4*)(ctx + i);
    float4 b = *(const float4*)(ctx + i + 4);
    union { uint4 v; unsigned short s[8]; } u;
    u.s[0] = f2bf(a.x); u.s[1] = f2bf(a.y); u.s[2] = f2bf(a.z); u.s[3] = f2bf(a.w);
    u.s[4] = f2bf(b.x); u.s[5] = f2bf(b.y); u.s[6] = f2bf(b.z); u.s[7] = f2bf(b.w);
    *(uint4*)(ctxb + i) = u.v;
  } else {
    size_t flat = ((size_t)(blk - 32768) * 256 + threadIdx.x) * 8;
    int row = (int)(flat >> 10);
    int c = (int)(flat & 1023);
    int b = row >> 12, p = row & 4095;
    union { uint4 v; unsigned short s[8]; } u;
    if (p <= 4032) {
      const float* sp = x + (((size_t)(b << 12) + p + 63) << 10) + c;
      float4 a = *(const float4*)sp;
      float4 d = *(const float4*)(sp + 4);
      u.s[0] = f2bf(a.x); u.s[1] = f2bf(a.y); u.s[2] = f2bf(a.z); u.s[3] = f2bf(a.w);
      u.s[4] = f2bf(d.x); u.s[5] = f2bf(d.y); u.s[6] = f2bf(d.z); u.s[7] = f2bf(d.w);
    } else {
      #pragma unroll
      for (int e = 0; e < 8; ++e) u.s[e] = 0;
    }
    *(uint4*)(xq + flat) = u.v;
  }
}

// ---------------------------------------------------------------------------
// Projection GEMM: C(Mx512) = A(MxK) * B^T(512xK), bf16 in, fp32 acc.
// 128x128x64 tile, 4 waves 2x2. XOR-swizzled LDS (<=2-way conflicts = free).
// MODE 0 (Q): 1-D grid, y=id&3, x=id>>2. Epilogue: RoPE on rows m%64==0
//             (q_pos_emb rows 1..63 are zero after the reference's pad).
// MODE 1 (KV): y=id&3, z=(id>>2)&1, x=id>>3 -> 8 siblings sharing an A panel
//             dispatch consecutively (L3 reuse). z=0: K + RoPE -> kb[m][n].
//             z=1: V -> LDS-transposed -> vtg[n][m] (coalesced b128 stores).
// ---------------------------------------------------------------------------
template <int MODE>
__global__ __launch_bounds__(256) void gemm_proj(const unsigned short* __restrict__ A,
                                                 const unsigned short* __restrict__ B0,
                                                 const unsigned short* __restrict__ B1,
                                                 unsigned short* __restrict__ out0,
                                                 unsigned short* __restrict__ out1,
                                                 const float* __restrict__ ck,
                                                 const float* __restrict__ sk,
                                                 const float* __restrict__ cq,
                                                 const float* __restrict__ sq,
                                                 int M, int K) {
  __shared__ unsigned short sh[16384];  // As = sh[0:8192], Bs = sh[8192:16384]
  unsigned short* As = sh;
  unsigned short* Bs = sh + 8192;

  int id = blockIdx.x;
  int x, y, z;
  if (MODE == 0) { y = id & 3; x = id >> 2; z = 0; }
  else           { y = id & 3; z = (id >> 2) & 1; x = id >> 3; }
  const unsigned short* B = z ? B1 : B0;
  int m0 = x * 128, n0 = y * 128;
  int tid = threadIdx.x, w = tid >> 6, lane = tid & 63;
  int wm = (w & 1) * 64, wn = (w >> 1) * 64;
  int Lrow = lane >> 3, Lc = lane & 7;
  int srcC = Lc ^ (Lrow & 7);

  f32x4 acc[4][4] = {};

  for (int k0 = 0; k0 < K; k0 += 64) {
    #pragma unroll
    for (int q = 0; q < 4; ++q) {
      int t = w * 4 + q;
      ldst16(A + (size_t)(m0 + t * 8 + Lrow) * K + (k0 + srcC * 8), (char*)As + t * 1024);
      ldst16(B + (size_t)(n0 + t * 8 + Lrow) * K + (k0 + srcC * 8), (char*)Bs + t * 1024);
    }
    __syncthreads();
    #pragma unroll
    for (int k32 = 0; k32 < 2; ++k32) {
      int c = k32 * 4 + (lane >> 4);
      bf16x8 af[4], bfr[4];
      #pragma unroll
      for (int mt = 0; mt < 4; ++mt) {
        int m = wm + mt * 16 + (lane & 15);
        af[mt] = *(const bf16x8*)((const char*)As + m * 128 + (c ^ (m & 7)) * 16);
      }
      #pragma unroll
      for (int nt = 0; nt < 4; ++nt) {
        int n = wn + nt * 16 + (lane & 15);
        bfr[nt] = *(const bf16x8*)((const char*)Bs + n * 128 + (c ^ (n & 7)) * 16);
      }
      #pragma unroll
      for (int mt = 0; mt < 4; ++mt)
        #pragma unroll
        for (int nt = 0; nt < 4; ++nt)
          acc[mt][nt] = __builtin_amdgcn_mfma_f32_16x16x32_bf16(af[mt], bfr[nt], acc[mt][nt], 0, 0, 0);
    }
    __syncthreads();
  }

  // C/D layout: col = lane&15, row = (lane>>4)*4 + reg (m89/m91 verified).
  // d = n&63 = nt*16 + (lane&15); rope partner d^32 lives at nt^2, same lane.
  if (MODE == 0) {
    #pragma unroll
    for (int mt = 0; mt < 4; ++mt)
      #pragma unroll
      for (int nt = 0; nt < 4; ++nt)
        #pragma unroll
        for (int r = 0; r < 4; ++r) {
          int m = m0 + wm + mt * 16 + (lane >> 4) * 4 + r;
          int n = n0 + wn + nt * 16 + (lane & 15);
          float val = acc[mt][nt][r];
          if ((m & 63) == 0) {  // only chunk-row 0 gets Q-RoPE
            int d = nt * 16 + (lane & 15);
            float partner = acc[mt][nt ^ 2][r];
            val = val * cq[d] + (nt < 2 ? -partner : partner) * sq[d];
          }
          out0[(size_t)m * 512 + n] = f2bf(val);
        }
  } else if (z == 0) {  // K with RoPE: fi = (m&127)*64 + d
    #pragma unroll
    for (int mt = 0; mt < 4; ++mt)
      #pragma unroll
      for (int r = 0; r < 4; ++r) {
        int m = m0 + wm + mt * 16 + (lane >> 4) * 4 + r;
        int fib = (m & 127) * 64;
        #pragma unroll
        for (int nt = 0; nt < 4; ++nt) {
          int n = n0 + wn + nt * 16 + (lane & 15);
          int d = nt * 16 + (lane & 15);
          float partner = acc[mt][nt ^ 2][r];
          float val = acc[mt][nt][r] * ck[fib + d] + (nt < 2 ? -partner : partner) * sk[fib + d];
          out0[(size_t)m * 512 + n] = f2bf(val);
        }
      }
  } else {  // V: transpose through LDS, store vtg[n][m] (row stride M)
    #pragma unroll
    for (int mt = 0; mt < 4; ++mt)
      #pragma unroll
      for (int nt = 0; nt < 4; ++nt)
        #pragma unroll
        for (int r = 0; r < 4; ++r) {
          int ml = wm + mt * 16 + (lane >> 4) * 4 + r;
          int nl = wn + nt * 16 + (lane & 15);
          int mc = ml >> 3, me = ml & 7;
          *(unsigned short*)((char*)sh + nl * 256 + ((mc ^ (nl & 15)) * 16) + me * 2) =
              f2bf(acc[mt][nt][r]);
        }
    __syncthreads();
    #pragma unroll
    for (int i = 0; i < 8; ++i) {
      int flat = i * 256 + tid;           // 128 rows x 16 chunks
      int nl = flat >> 4, mc = flat & 15;
      uint4 v = *(const uint4*)((const char*)sh + nl * 256 + ((mc ^ (nl & 15)) * 16));
      *(uint4*)(out1 + (size_t)(n0 + nl) * M + m0 + mc * 8) = v;
    }
  }
}

// ---------------------------------------------------------------------------
// Output GEMM: out fp32 = A(16384x512) * Wo^T(1024x512) + bias, row-shifted:
// out[b, t+63] = row(b*4096+t) for t<=4032. 1-D grid: y=id&7, x=id>>3.
// ---------------------------------------------------------------------------
__global__ __launch_bounds__(256) void gemm_out(const unsigned short* __restrict__ A,
                                                const unsigned short* __restrict__ B,
                                                const float* __restrict__ bias,
                                                float* __restrict__ out) {
  __shared__ unsigned short sh[16384];
  unsigned short* As = sh;
  unsigned short* Bs = sh + 8192;
  const int K = 512, N = 1024;
  int id = blockIdx.x;
  int y = id & 7, x = id >> 3;
  int m0 = x * 128, n0 = y * 128;
  int tid = threadIdx.x, w = tid >> 6, lane = tid & 63;
  int wm = (w & 1) * 64, wn = (w >> 1) * 64;
  int Lrow = lane >> 3, Lc = lane & 7;
  int srcC = Lc ^ (Lrow & 7);

  f32x4 acc[4][4] = {};

  for (int k0 = 0; k0 < K; k0 += 64) {
    #pragma unroll
    for (int q = 0; q < 4; ++q) {
      int t = w * 4 + q;
      ldst16(A + (size_t)(m0 + t * 8 + Lrow) * K + (k0 + srcC * 8), (char*)As + t * 1024);
      ldst16(B + (size_t)(n0 + t * 8 + Lrow) * K + (k0 + srcC * 8), (char*)Bs + t * 1024);
    }
    __syncthreads();
    #pragma unroll
    for (int k32 = 0; k32 < 2; ++k32) {
      int c = k32 * 4 + (lane >> 4);
      bf16x8 af[4], bfr[4];
      #pragma unroll
      for (int mt = 0; mt < 4; ++mt) {
        int m = wm + mt * 16 + (lane & 15);
        af[mt] = *(const bf16x8*)((const char*)As + m * 128 + (c ^ (m & 7)) * 16);
      }
      #pragma unroll
      for (int nt = 0; nt < 4; ++nt) {
        int n = wn + nt * 16 + (lane & 15);
        bfr[nt] = *(const bf16x8*)((const char*)Bs + n * 128 + (c ^ (n & 7)) * 16);
      }
      #pragma unroll
      for (int mt = 0; mt < 4; ++mt)
        #pragma unroll
        for (int nt = 0; nt < 4; ++nt)
          acc[mt][nt] = __builtin_amdgcn_mfma_f32_16x16x32_bf16(af[mt], bfr[nt], acc[mt][nt], 0, 0, 0);
    }
    __syncthreads();
  }
  #pragma unroll
  for (int mt = 0; mt < 4; ++mt)
    #pragma unroll
    for (int nt = 0; nt < 4; ++nt)
      #pragma unroll
      for (int r = 0; r < 4; ++r) {
        int m = m0 + wm + mt * 16 + (lane >> 4) * 4 + r;
        int n = n0 + wn + nt * 16 + (lane & 15);
        int b = m >> 12, t = m & 4095;
        if (t <= 4032)
          out[((size_t)((b << 12) + t + 63)) * N + n] = acc[mt][nt][r] + bias[n];
      }
}

// ---------------------------------------------------------------------------
// Fused attention per (bc, h): sim = q k^T (MFMA), softmax w/ null key (fp32,
// registers + shuffles), P -> LDS bf16, V^T staged from vtg via ldst16 into
// the ks buffer, o = P v (MFMA), null_v + normalize in fp32 epilogue.
// Grid 1-D 2048: bc=(id&7)+8*(id>>6), h=(id>>3)&7 -> the 8 h-siblings of a bc
// land on one XCD back-to-back (kb/vtg rows shared through its L2).
// ---------------------------------------------------------------------------
__global__ __launch_bounds__(256) void attn_kernel(const unsigned short* __restrict__ qb,
                                                   const unsigned short* __restrict__ kb,
                                                   const unsigned short* __restrict__ vtg,
                                                   const float* __restrict__ nullk,
                                                   const float* __restrict__ nullv,
                                                   unsigned short* __restrict__ ob) {
  __shared__ unsigned short qs[64 * 64];    // 8 KB  [i][d]
  __shared__ unsigned short ks[256 * 64];   // 32 KB [j][d]; reused as vt[d][j]
  __shared__ unsigned short ps[64 * 256];   // 32 KB [i][j]
  __shared__ float rnull[64];
  __shared__ float rsum[64];
  int id = blockIdx.x;
  int bc = (id & 7) + 8 * (id >> 6);
  int h = (id >> 3) & 7;
  int tid = threadIdx.x, w = tid >> 6, lane = tid & 63;
  int Lrow = lane >> 3, Lc = lane & 7, srcC = Lc ^ (Lrow & 7);

  #pragma unroll
  for (int q8 = 0; q8 < 2; ++q8) {
    int t = w * 2 + q8;
    ldst16(qb + (size_t)(bc * 64 + t * 8 + Lrow) * 512 + h * 64 + srcC * 8, (char*)qs + t * 1024);
  }
  #pragma unroll
  for (int q8 = 0; q8 < 8; ++q8) {
    int t = w * 8 + q8;
    ldst16(kb + (size_t)(bc * 256 + t * 8 + Lrow) * 512 + h * 64 + srcC * 8, (char*)ks + t * 1024);
  }
  __syncthreads();

  // null-key sims: 4 lanes per row, 16 d each, combine via shuffles.
  {
    int rl = lane >> 2, part = lane & 3;
    int row = w * 16 + rl;
    float s = 0.f;
    #pragma unroll
    for (int e = 0; e < 16; ++e) {
      int d = part * 16 + e;
      unsigned short qv = *(const unsigned short*)((const char*)qs + row * 128 +
                                                   (((d >> 3) ^ (row & 7)) * 16) + (d & 7) * 2);
      s += bf2f(qv) * nullk[h * 64 + d];
    }
    s += __shfl_xor(s, 1);
    s += __shfl_xor(s, 2);
    if (part == 0) rnull[row] = s;
  }

  // sim: wave w owns rows [16w,16w+16), 16 n-tiles of 16 keys.
  f32x4 acc[16] = {};
  #pragma unroll
  for (int k32 = 0; k32 < 2; ++k32) {
    int c = k32 * 4 + (lane >> 4);
    int m = w * 16 + (lane & 15);
    bf16x8 a = *(const bf16x8*)((const char*)qs + m * 128 + (c ^ (m & 7)) * 16);
    #pragma unroll
    for (int nt = 0; nt < 16; ++nt) {
      int n = nt * 16 + (lane & 15);
      bf16x8 b = *(const bf16x8*)((const char*)ks + n * 128 + (c ^ (n & 7)) * 16);
      acc[nt] = __builtin_amdgcn_mfma_f32_16x16x32_bf16(a, b, acc[nt], 0, 0, 0);
    }
  }

  // softmax (unnormalized) per row.
  int g = lane >> 4;
  #pragma unroll
  for (int r = 0; r < 4; ++r) {
    int row = w * 16 + g * 4 + r;
    float mx = -3.0e38f;
    #pragma unroll
    for (int nt = 0; nt < 16; ++nt) mx = fmaxf(mx, acc[nt][r]);
    mx = fmaxf(mx, __shfl_xor(mx, 1));
    mx = fmaxf(mx, __shfl_xor(mx, 2));
    mx = fmaxf(mx, __shfl_xor(mx, 4));
    mx = fmaxf(mx, __shfl_xor(mx, 8));
    float ns = rnull[row];
    float mm = fmaxf(mx, ns);
    float s = 0.f;
    #pragma unroll
    for (int nt = 0; nt < 16; ++nt) {
      float p = __expf(acc[nt][r] - mm);
      acc[nt][r] = p;
      s += p;
    }
    s += __shfl_xor(s, 1);
    s += __shfl_xor(s, 2);
    s += __shfl_xor(s, 4);
    s += __shfl_xor(s, 8);
    float en = __expf(ns - mm);
    s += en;
    if ((lane & 15) == 0) {
      rsum[row] = s;
      rnull[row] = en;
    }
  }

  // P -> LDS bf16 (A-operand layout for PV).
  #pragma unroll
  for (int nt = 0; nt < 16; ++nt)
    #pragma unroll
    for (int r = 0; r < 4; ++r) {
      int row = w * 16 + g * 4 + r;
      int col = nt * 16 + (lane & 15);
      *(unsigned short*)((char*)ps + row * 512 + (((col >> 3) ^ (row & 7)) * 16) + (col & 7) * 2) =
          f2bf(acc[nt][r]);
    }
  __syncthreads();  // all waves done reading ks

  // stage V^T (pre-transposed in global) into ks via ldst16.
  #pragma unroll
  for (int q8 = 0; q8 < 8; ++q8) {
    int t = w * 8 + q8;                 // 1KB region = rows 2t, 2t+1
    int dd = t * 2 + (lane >> 5);
    int cl = (lane & 31) ^ (dd & 7);    // logical chunk for this phys slot
    ldst16(vtg + (size_t)(h * 64 + dd) * 65536 + bc * 256 + cl * 8, (char*)ks + t * 1024);
  }
  __syncthreads();

  // o = P v : k over 256 keys, 4 n-tiles of d.
  f32x4 oacc[4] = {};
  #pragma unroll
  for (int k32 = 0; k32 < 8; ++k32) {
    int c = k32 * 4 + (lane >> 4);
    int m = w * 16 + (lane & 15);
    bf16x8 a = *(const bf16x8*)((const char*)ps + m * 512 + (c ^ (m & 7)) * 16);
    #pragma unroll
    for (int nt = 0; nt < 4; ++nt) {
      int n = nt * 16 + (lane & 15);
      bf16x8 b = *(const bf16x8*)((const char*)ks + n * 512 + (c ^ (n & 7)) * 16);
      oacc[nt] = __builtin_amdgcn_mfma_f32_16x16x32_bf16(a, b, oacc[nt], 0, 0, 0);
    }
  }
  #pragma unroll
  for (int nt = 0; nt < 4; ++nt)
    #pragma unroll
    for (int r = 0; r < 4; ++r) {
      int row = w * 16 + g * 4 + r;
      int d = nt * 16 + (lane & 15);
      float o = oacc[nt][r] + rnull[row] * nullv[h * 64 + d];
      o /= rsum[row];
      ob[((size_t)(bc * 64 + row) * 8 + h) * 64 + d] = f2bf(o);
    }
}

// ---------------------------------------------------------------------------
extern "C" void kernel_launch(void* const* d_in, const int* in_sizes, int n_in,
                              void* d_out, int out_size, void* d_ws, size_t ws_size,
                              hipStream_t stream) {
  const float* x = (const float*)d_in[0];
  const float* ctx = (const float*)d_in[1];
  const float* qpe = (const float*)d_in[2];
  const float* kpe = (const float*)d_in[3];
  const float* Wq = (const float*)d_in[4];
  const float* Wk = (const float*)d_in[5];
  const float* Wv = (const float*)d_in[6];
  const float* Wo = (const float*)d_in[7];
  const float* bo = (const float*)d_in[8];
  const float* nk = (const float*)d_in[9];
  const float* nv = (const float*)d_in[10];
  float* out = (float*)d_out;
  char* ws = (char*)d_ws;

  unsigned short* xq   = (unsigned short*)(ws + 0);           // 33,554,432
  unsigned short* ctxb = (unsigned short*)(ws + 33554432);    // 134,217,728
  unsigned short* Wqt  = (unsigned short*)(ws + 167772160);   // 1,048,576
  unsigned short* Wkt  = (unsigned short*)(ws + 168820736);   // 1,048,576
  unsigned short* Wvt  = (unsigned short*)(ws + 169869312);   // 1,048,576
  unsigned short* Wot  = (unsigned short*)(ws + 170917888);   // 1,048,576
  unsigned short* qb   = (unsigned short*)(ws + 171966464);   // 16,777,216
  unsigned short* kb   = (unsigned short*)(ws + 188743680);   // 67,108,864
  unsigned short* vtg  = (unsigned short*)(ws + 255852544);   // 67,108,864 (V^T: [512][65536])
  unsigned short* obuf = (unsigned short*)(ws + 322961408);   // 16,777,216
  float* cosk = (float*)(ws + 339738624);                     // 32,768
  float* sink = (float*)(ws + 339771392);                     // 32,768
  float* cosq = (float*)(ws + 339804160);                     // 256
  float* sinq = (float*)(ws + 339804416);                     // 256

  prep_k<<<8476, 256, 0, stream>>>(Wq, Wk, Wv, Wo, qpe, kpe, Wqt, Wkt, Wvt, Wot,
                                   cosk, sink, cosq, sinq, out);
  cast_k<<<40960, 256, 0, stream>>>(ctx, x, ctxb, xq);

  // Q projection (16384x1024)@(1024x512), RoPE fused
  gemm_proj<0><<<512, 256, 0, stream>>>(xq, Wqt, Wqt, qb, nullptr,
                                        cosk, sink, cosq, sinq, 16384, 1024);
  // K+V projection (65536x1024)@(1024x512) x2; K RoPE'd, V transposed
  gemm_proj<1><<<4096, 256, 0, stream>>>(ctxb, Wkt, Wvt, kb, vtg,
                                         cosk, sink, cosq, sinq, 65536, 1024);

  attn_kernel<<<2048, 256, 0, stream>>>(qb, kb, vtg, nk, nv, obuf);

  // Output: (16384x512)@(512x1024) + bias, shifted rows
  gemm_out<<<1024, 256, 0, stream>>>(obuf, Wot, bo, out);
}

// Round 3
// 764.635 us; speedup vs baseline: 1.0637x; 1.0522x over previous
//
#include <hip/hip_runtime.h>

// ChunkedCrossAttention on MI355X (gfx950) — round 3.
// Changes vs round 2:
//  - cast kernel ELIMINATED: GEMMs read fp32 A directly, packing to bf16 in
//    staging via v_perm_b32 (RTZ, 1 inst / 2 elems). B stays global_load_lds.
//  - XCD-pinned swizzle: blocks sharing an A panel get ids = same (mod 8)
//    within a 64-id window -> panel lives in ONE XCD's L2 (round 2 put
//    siblings on 8 different XCDs - wrong).
//  - attn: max-subtraction dropped (scores are O(1); exp2 safe), softmax VALU cut.
//  - RoPE-K / RoPE-Q / V-transpose epilogue fusions kept.

#define DEV __device__ __forceinline__

typedef __bf16 bf16x8 __attribute__((ext_vector_type(8)));
typedef float f32x4 __attribute__((ext_vector_type(4)));

DEV unsigned short f2bf(float f) {
  union { float f; unsigned int u; } v; v.f = f;
  unsigned int u = v.u;
  unsigned int r = (u + 0x7FFFu + ((u >> 16) & 1u)) >> 16;  // RNE
  return (unsigned short)r;
}
DEV float bf2f(unsigned short h) {
  union { unsigned int u; float f; } v; v.u = ((unsigned int)h) << 16;
  return v.f;
}
// pack two fp32 -> two bf16 (RTZ): result = [bf16(lo), bf16(hi)]
DEV unsigned int pkbf(unsigned int hi, unsigned int lo) {
  return __builtin_amdgcn_perm(hi, lo, 0x07060302u);
}

// async global->LDS, 16B per lane; LDS dest = wave-uniform base + lane*16
DEV void ldst16(const void* g, void* l) {
  __builtin_amdgcn_global_load_lds(
      (const __attribute__((address_space(1))) void*)g,
      (__attribute__((address_space(3))) void*)l, 16, 0, 0);
}

// ---------------------------------------------------------------------------
// prep: weight transpose+cast (+SCALE fold), zero rows 0..62 per batch of out,
// rope cos/sin tables. One launch.
// ---------------------------------------------------------------------------
__global__ __launch_bounds__(256) void prep_k(const float* __restrict__ Wq,
                                              const float* __restrict__ Wk,
                                              const float* __restrict__ Wv,
                                              const float* __restrict__ Wo,
                                              const float* __restrict__ qpe,
                                              const float* __restrict__ kpe,
                                              unsigned short* __restrict__ Wqt,
                                              unsigned short* __restrict__ Wkt,
                                              unsigned short* __restrict__ Wvt,
                                              unsigned short* __restrict__ Wot,
                                              float* __restrict__ ck, float* __restrict__ sk,
                                              float* __restrict__ cq, float* __restrict__ sq,
                                              float* __restrict__ out) {
  int blk = blockIdx.x;
  if (blk < 8192) {
    int idx = blk * 256 + threadIdx.x;     // 0..2097151
    int which = idx >> 19;                 // 0..3
    int loc = idx & 524287;
    if (which < 3) {                       // Wq/Wk/Wv: (1024x512) -> (512x1024)
      int k = loc & 1023, n = loc >> 10;
      const float* W = which == 0 ? Wq : (which == 1 ? Wk : Wv);
      unsigned short* Wt = which == 0 ? Wqt : (which == 1 ? Wkt : Wvt);
      float scale = which == 0 ? 0.125f : 1.0f;
      Wt[loc] = f2bf(W[(size_t)k * 512 + n] * scale);
    } else {                               // Wo: (512x1024) -> (1024x512)
      int k = loc & 511, n = loc >> 9;
      Wot[loc] = f2bf(Wo[(size_t)k * 1024 + n]);
    }
  } else if (blk < 8444) {                 // zero rows 0..62 of each batch
    int r = blk - 8192;
    int b = r / 63, rr = r % 63;
    float4 z = {0.f, 0.f, 0.f, 0.f};
    *(float4*)(out + (((size_t)(b * 4096 + rr)) << 10) + threadIdx.x * 4) = z;
  } else {                                 // rope tables
    int t = (blk - 8444) * 256 + threadIdx.x;  // 0..8191
    float f = kpe[t];
    ck[t] = cosf(f);
    sk[t] = sinf(f);
    if (t < 64) {
      float g = qpe[63 * 64 + t];
      cq[t] = cosf(g);
      sq[t] = sinf(g);
    }
  }
}

// ---------------------------------------------------------------------------
// Projection GEMM with FUSED fp32->bf16 A-cast: C(Mx512) = cast(Af)(MxK) *
// B^T(512xK). A staged via global fp32 loads + v_perm pack + ds_write_b128
// (same swizzled LDS layout as ldst16); B staged via global_load_lds.
// MODE 0 (Q): A row m reads x[b, p+63] (p=m&4095; zero if p>4032). RoPE-Q on
//             rows m%64==0. Swizzle: x=(id%8)+8*(id/32), y=(id/8)%4.
// MODE 1 (KV): A = ctx rows directly. z=0: K + RoPE -> kb. z=1: V -> LDS
//             transpose -> vtg[n][m]. Swizzle: x=(id%8)+8*(id/64),
//             j=(id/8)%8, y=j&3, z=j>>2  (8 siblings of a panel -> one XCD).
// ---------------------------------------------------------------------------
template <int MODE>
__global__ __launch_bounds__(256) void gemm_proj(const float* __restrict__ Af,
                                                 const unsigned short* __restrict__ B0,
                                                 const unsigned short* __restrict__ B1,
                                                 unsigned short* __restrict__ out0,
                                                 unsigned short* __restrict__ out1,
                                                 const float* __restrict__ ck,
                                                 const float* __restrict__ sk,
                                                 const float* __restrict__ cq,
                                                 const float* __restrict__ sq) {
  __shared__ unsigned short sh[16384];  // As = sh[0:8192], Bs = sh[8192:16384]
  unsigned short* As = sh;
  unsigned short* Bs = sh + 8192;
  const int K = 1024;

  int id = blockIdx.x;
  int x, y, z;
  if (MODE == 0) { x = (id & 7) + 8 * (id >> 5); y = (id >> 3) & 3; z = 0; }
  else           { x = (id & 7) + 8 * (id >> 6); int j = (id >> 3) & 7; y = j & 3; z = j >> 2; }
  const unsigned short* B = z ? B1 : B0;
  int m0 = x * 128, n0 = y * 128;
  int tid = threadIdx.x, w = tid >> 6, lane = tid & 63;
  int wm = (w & 1) * 64, wn = (w >> 1) * 64;
  int Lrow = lane >> 3, Lc = lane & 7;
  int srcC = Lc ^ (Lrow & 7);

  // per-thread A source rows (4 chunks) + validity
  const float* asrc[4];
  bool avalid[4];
  #pragma unroll
  for (int q = 0; q < 4; ++q) {
    int t = w * 4 + q;
    int gm = m0 + t * 8 + Lrow;
    if (MODE == 0) {
      int b = gm >> 12, p = gm & 4095;
      avalid[q] = (p <= 4032);
      asrc[q] = Af + (((size_t)(b << 12) + p + 63) << 10) + srcC * 8;
    } else {
      avalid[q] = true;
      asrc[q] = Af + (size_t)gm * 1024 + srcC * 8;
    }
  }

  f32x4 acc[4][4] = {};

  for (int k0 = 0; k0 < K; k0 += 64) {
    #pragma unroll
    for (int q = 0; q < 4; ++q) {
      int t = w * 4 + q;
      uint4 lo = {0, 0, 0, 0}, hi = {0, 0, 0, 0};
      if (avalid[q]) {
        lo = *(const uint4*)(asrc[q] + k0);
        hi = *(const uint4*)(asrc[q] + k0 + 4);
      }
      uint4 pk;
      pk.x = pkbf(lo.y, lo.x);
      pk.y = pkbf(lo.w, lo.z);
      pk.z = pkbf(hi.y, hi.x);
      pk.w = pkbf(hi.w, hi.z);
      *(uint4*)((char*)As + t * 1024 + lane * 16) = pk;
      ldst16(B + (size_t)(n0 + t * 8 + Lrow) * K + (k0 + srcC * 8), (char*)Bs + t * 1024);
    }
    __syncthreads();
    #pragma unroll
    for (int k32 = 0; k32 < 2; ++k32) {
      int c = k32 * 4 + (lane >> 4);
      bf16x8 af[4], bfr[4];
      #pragma unroll
      for (int mt = 0; mt < 4; ++mt) {
        int m = wm + mt * 16 + (lane & 15);
        af[mt] = *(const bf16x8*)((const char*)As + m * 128 + (c ^ (m & 7)) * 16);
      }
      #pragma unroll
      for (int nt = 0; nt < 4; ++nt) {
        int n = wn + nt * 16 + (lane & 15);
        bfr[nt] = *(const bf16x8*)((const char*)Bs + n * 128 + (c ^ (n & 7)) * 16);
      }
      #pragma unroll
      for (int mt = 0; mt < 4; ++mt)
        #pragma unroll
        for (int nt = 0; nt < 4; ++nt)
          acc[mt][nt] = __builtin_amdgcn_mfma_f32_16x16x32_bf16(af[mt], bfr[nt], acc[mt][nt], 0, 0, 0);
    }
    __syncthreads();
  }

  // C/D layout: col = lane&15, row = (lane>>4)*4 + reg (m89/m91 verified).
  if (MODE == 0) {
    #pragma unroll
    for (int mt = 0; mt < 4; ++mt)
      #pragma unroll
      for (int nt = 0; nt < 4; ++nt)
        #pragma unroll
        for (int r = 0; r < 4; ++r) {
          int m = m0 + wm + mt * 16 + (lane >> 4) * 4 + r;
          int n = n0 + wn + nt * 16 + (lane & 15);
          float val = acc[mt][nt][r];
          if ((m & 63) == 0) {  // only chunk-row 0 gets Q-RoPE
            int d = nt * 16 + (lane & 15);
            float partner = acc[mt][nt ^ 2][r];
            val = val * cq[d] + (nt < 2 ? -partner : partner) * sq[d];
          }
          out0[(size_t)m * 512 + n] = f2bf(val);
        }
  } else if (z == 0) {  // K with RoPE: fi = (m&127)*64 + d
    #pragma unroll
    for (int mt = 0; mt < 4; ++mt)
      #pragma unroll
      for (int r = 0; r < 4; ++r) {
        int m = m0 + wm + mt * 16 + (lane >> 4) * 4 + r;
        int fib = (m & 127) * 64;
        #pragma unroll
        for (int nt = 0; nt < 4; ++nt) {
          int n = n0 + wn + nt * 16 + (lane & 15);
          int d = nt * 16 + (lane & 15);
          float partner = acc[mt][nt ^ 2][r];
          float val = acc[mt][nt][r] * ck[fib + d] + (nt < 2 ? -partner : partner) * sk[fib + d];
          out0[(size_t)m * 512 + n] = f2bf(val);
        }
      }
  } else {  // V: transpose through LDS, store vtg[n][m] (row stride 65536)
    #pragma unroll
    for (int mt = 0; mt < 4; ++mt)
      #pragma unroll
      for (int nt = 0; nt < 4; ++nt)
        #pragma unroll
        for (int r = 0; r < 4; ++r) {
          int ml = wm + mt * 16 + (lane >> 4) * 4 + r;
          int nl = wn + nt * 16 + (lane & 15);
          int mc = ml >> 3, me = ml & 7;
          *(unsigned short*)((char*)sh + nl * 256 + ((mc ^ (nl & 15)) * 16) + me * 2) =
              f2bf(acc[mt][nt][r]);
        }
    __syncthreads();
    #pragma unroll
    for (int i = 0; i < 8; ++i) {
      int flat = i * 256 + tid;           // 128 rows x 16 chunks
      int nl = flat >> 4, mc = flat & 15;
      uint4 v = *(const uint4*)((const char*)sh + nl * 256 + ((mc ^ (nl & 15)) * 16));
      *(uint4*)(out1 + (size_t)(n0 + nl) * 65536 + m0 + mc * 8) = v;
    }
  }
}

// ---------------------------------------------------------------------------
// Output GEMM: out fp32 = A(16384x512) * Wo^T(1024x512) + bias, row-shifted:
// out[b, t+63] = row(b*4096+t) for t<=4032. Swizzle: x=(id%8)+8*(id/64),
// y=(id/8)%8 (8 siblings of an A panel -> one XCD).
// ---------------------------------------------------------------------------
__global__ __launch_bounds__(256) void gemm_out(const unsigned short* __restrict__ A,
                                                const unsigned short* __restrict__ B,
                                                const float* __restrict__ bias,
                                                float* __restrict__ out) {
  __shared__ unsigned short sh[16384];
  unsigned short* As = sh;
  unsigned short* Bs = sh + 8192;
  const int K = 512, N = 1024;
  int id = blockIdx.x;
  int x = (id & 7) + 8 * (id >> 6), y = (id >> 3) & 7;
  int m0 = x * 128, n0 = y * 128;
  int tid = threadIdx.x, w = tid >> 6, lane = tid & 63;
  int wm = (w & 1) * 64, wn = (w >> 1) * 64;
  int Lrow = lane >> 3, Lc = lane & 7;
  int srcC = Lc ^ (Lrow & 7);

  f32x4 acc[4][4] = {};

  for (int k0 = 0; k0 < K; k0 += 64) {
    #pragma unroll
    for (int q = 0; q < 4; ++q) {
      int t = w * 4 + q;
      ldst16(A + (size_t)(m0 + t * 8 + Lrow) * K + (k0 + srcC * 8), (char*)As + t * 1024);
      ldst16(B + (size_t)(n0 + t * 8 + Lrow) * K + (k0 + srcC * 8), (char*)Bs + t * 1024);
    }
    __syncthreads();
    #pragma unroll
    for (int k32 = 0; k32 < 2; ++k32) {
      int c = k32 * 4 + (lane >> 4);
      bf16x8 af[4], bfr[4];
      #pragma unroll
      for (int mt = 0; mt < 4; ++mt) {
        int m = wm + mt * 16 + (lane & 15);
        af[mt] = *(const bf16x8*)((const char*)As + m * 128 + (c ^ (m & 7)) * 16);
      }
      #pragma unroll
      for (int nt = 0; nt < 4; ++nt) {
        int n = wn + nt * 16 + (lane & 15);
        bfr[nt] = *(const bf16x8*)((const char*)Bs + n * 128 + (c ^ (n & 7)) * 16);
      }
      #pragma unroll
      for (int mt = 0; mt < 4; ++mt)
        #pragma unroll
        for (int nt = 0; nt < 4; ++nt)
          acc[mt][nt] = __builtin_amdgcn_mfma_f32_16x16x32_bf16(af[mt], bfr[nt], acc[mt][nt], 0, 0, 0);
    }
    __syncthreads();
  }
  #pragma unroll
  for (int mt = 0; mt < 4; ++mt)
    #pragma unroll
    for (int nt = 0; nt < 4; ++nt)
      #pragma unroll
      for (int r = 0; r < 4; ++r) {
        int m = m0 + wm + mt * 16 + (lane >> 4) * 4 + r;
        int n = n0 + wn + nt * 16 + (lane & 15);
        int b = m >> 12, t = m & 4095;
        if (t <= 4032)
          out[((size_t)((b << 12) + t + 63)) * N + n] = acc[mt][nt][r] + bias[n];
      }
}

// ---------------------------------------------------------------------------
// Fused attention per (bc, h): sim = q k^T (MFMA), softmax WITHOUT max-sub
// (scores are O(1); exp overflow-safe; shift-invariant), P -> LDS bf16,
// V^T staged from vtg via ldst16, o = P v (MFMA), null_v + normalize.
// ---------------------------------------------------------------------------
__global__ __launch_bounds__(256) void attn_kernel(const unsigned short* __restrict__ qb,
                                                   const unsigned short* __restrict__ kb,
                                                   const unsigned short* __restrict__ vtg,
                                                   const float* __restrict__ nullk,
                                                   const float* __restrict__ nullv,
                                                   unsigned short* __restrict__ ob) {
  __shared__ unsigned short qs[64 * 64];    // 8 KB  [i][d]
  __shared__ unsigned short ks[256 * 64];   // 32 KB [j][d]; reused as vt[d][j]
  __shared__ unsigned short ps[64 * 256];   // 32 KB [i][j]
  __shared__ float rnull[64];
  __shared__ float rsum[64];
  int id = blockIdx.x;
  int bc = (id & 7) + 8 * (id >> 6);
  int h = (id >> 3) & 7;
  int tid = threadIdx.x, w = tid >> 6, lane = tid & 63;
  int Lrow = lane >> 3, Lc = lane & 7, srcC = Lc ^ (Lrow & 7);

  #pragma unroll
  for (int q8 = 0; q8 < 2; ++q8) {
    int t = w * 2 + q8;
    ldst16(qb + (size_t)(bc * 64 + t * 8 + Lrow) * 512 + h * 64 + srcC * 8, (char*)qs + t * 1024);
  }
  #pragma unroll
  for (int q8 = 0; q8 < 8; ++q8) {
    int t = w * 8 + q8;
    ldst16(kb + (size_t)(bc * 256 + t * 8 + Lrow) * 512 + h * 64 + srcC * 8, (char*)ks + t * 1024);
  }
  __syncthreads();

  // null-key sims: 4 lanes per row, 16 d each, combine via shuffles.
  {
    int rl = lane >> 2, part = lane & 3;
    int row = w * 16 + rl;
    float s = 0.f;
    #pragma unroll
    for (int e = 0; e < 16; ++e) {
      int d = part * 16 + e;
      unsigned short qv = *(const unsigned short*)((const char*)qs + row * 128 +
                                                   (((d >> 3) ^ (row & 7)) * 16) + (d & 7) * 2);
      s += bf2f(qv) * nullk[h * 64 + d];
    }
    s += __shfl_xor(s, 1);
    s += __shfl_xor(s, 2);
    if (part == 0) rnull[row] = __expf(s);
  }

  // sim: wave w owns rows [16w,16w+16), 16 n-tiles of 16 keys.
  f32x4 acc[16] = {};
  #pragma unroll
  for (int k32 = 0; k32 < 2; ++k32) {
    int c = k32 * 4 + (lane >> 4);
    int m = w * 16 + (lane & 15);
    bf16x8 a = *(const bf16x8*)((const char*)qs + m * 128 + (c ^ (m & 7)) * 16);
    #pragma unroll
    for (int nt = 0; nt < 16; ++nt) {
      int n = nt * 16 + (lane & 15);
      bf16x8 b = *(const bf16x8*)((const char*)ks + n * 128 + (c ^ (n & 7)) * 16);
      acc[nt] = __builtin_amdgcn_mfma_f32_16x16x32_bf16(a, b, acc[nt], 0, 0, 0);
    }
  }

  // exp + row-sum (no max subtraction).
  int g = lane >> 4;
  #pragma unroll
  for (int r = 0; r < 4; ++r) {
    int row = w * 16 + g * 4 + r;
    float s = 0.f;
    #pragma unroll
    for (int nt = 0; nt < 16; ++nt) {
      float p = __expf(acc[nt][r]);
      acc[nt][r] = p;
      s += p;
    }
    s += __shfl_xor(s, 1);
    s += __shfl_xor(s, 2);
    s += __shfl_xor(s, 4);
    s += __shfl_xor(s, 8);
    if ((lane & 15) == 0) rsum[row] = s + rnull[row];
  }

  // P -> LDS bf16 (A-operand layout for PV).
  #pragma unroll
  for (int nt = 0; nt < 16; ++nt)
    #pragma unroll
    for (int r = 0; r < 4; ++r) {
      int row = w * 16 + g * 4 + r;
      int col = nt * 16 + (lane & 15);
      *(unsigned short*)((char*)ps + row * 512 + (((col >> 3) ^ (row & 7)) * 16) + (col & 7) * 2) =
          f2bf(acc[nt][r]);
    }
  __syncthreads();  // all waves done reading ks

  // stage V^T (pre-transposed in global) into ks via ldst16.
  #pragma unroll
  for (int q8 = 0; q8 < 8; ++q8) {
    int t = w * 8 + q8;                 // 1KB region = rows 2t, 2t+1
    int dd = t * 2 + (lane >> 5);
    int cl = (lane & 31) ^ (dd & 7);    // logical chunk for this phys slot
    ldst16(vtg + (size_t)(h * 64 + dd) * 65536 + bc * 256 + cl * 8, (char*)ks + t * 1024);
  }
  __syncthreads();

  // o = P v : k over 256 keys, 4 n-tiles of d.
  f32x4 oacc[4] = {};
  #pragma unroll
  for (int k32 = 0; k32 < 8; ++k32) {
    int c = k32 * 4 + (lane >> 4);
    int m = w * 16 + (lane & 15);
    bf16x8 a = *(const bf16x8*)((const char*)ps + m * 512 + (c ^ (m & 7)) * 16);
    #pragma unroll
    for (int nt = 0; nt < 4; ++nt) {
      int n = nt * 16 + (lane & 15);
      bf16x8 b = *(const bf16x8*)((const char*)ks + n * 512 + (c ^ (n & 7)) * 16);
      oacc[nt] = __builtin_amdgcn_mfma_f32_16x16x32_bf16(a, b, oacc[nt], 0, 0, 0);
    }
  }
  #pragma unroll
  for (int nt = 0; nt < 4; ++nt)
    #pragma unroll
    for (int r = 0; r < 4; ++r) {
      int row = w * 16 + g * 4 + r;
      int d = nt * 16 + (lane & 15);
      float o = oacc[nt][r] + rnull[row] * nullv[h * 64 + d];
      o /= rsum[row];
      ob[((size_t)(bc * 64 + row) * 8 + h) * 64 + d] = f2bf(o);
    }
}

// ---------------------------------------------------------------------------
extern "C" void kernel_launch(void* const* d_in, const int* in_sizes, int n_in,
                              void* d_out, int out_size, void* d_ws, size_t ws_size,
                              hipStream_t stream) {
  const float* x = (const float*)d_in[0];
  const float* ctx = (const float*)d_in[1];
  const float* qpe = (const float*)d_in[2];
  const float* kpe = (const float*)d_in[3];
  const float* Wq = (const float*)d_in[4];
  const float* Wk = (const float*)d_in[5];
  const float* Wv = (const float*)d_in[6];
  const float* Wo = (const float*)d_in[7];
  const float* bo = (const float*)d_in[8];
  const float* nk = (const float*)d_in[9];
  const float* nv = (const float*)d_in[10];
  float* out = (float*)d_out;
  char* ws = (char*)d_ws;

  unsigned short* Wqt  = (unsigned short*)(ws + 0);          // 1,048,576
  unsigned short* Wkt  = (unsigned short*)(ws + 1048576);    // 1,048,576
  unsigned short* Wvt  = (unsigned short*)(ws + 2097152);    // 1,048,576
  unsigned short* Wot  = (unsigned short*)(ws + 3145728);    // 1,048,576
  unsigned short* qb   = (unsigned short*)(ws + 4194304);    // 16,777,216
  unsigned short* kb   = (unsigned short*)(ws + 20971520);   // 67,108,864
  unsigned short* vtg  = (unsigned short*)(ws + 88080384);   // 67,108,864 (V^T: [512][65536])
  unsigned short* obuf = (unsigned short*)(ws + 155189248);  // 16,777,216
  float* cosk = (float*)(ws + 171966464);                    // 32,768
  float* sink = (float*)(ws + 171999232);                    // 32,768
  float* cosq = (float*)(ws + 172032000);                    // 256
  float* sinq = (float*)(ws + 172032256);                    // 256

  prep_k<<<8476, 256, 0, stream>>>(Wq, Wk, Wv, Wo, qpe, kpe, Wqt, Wkt, Wvt, Wot,
                                   cosk, sink, cosq, sinq, out);

  // Q projection (16384x1024)@(1024x512), fp32-A fused cast + shift, RoPE fused
  gemm_proj<0><<<512, 256, 0, stream>>>(x, Wqt, Wqt, qb, nullptr,
                                        cosk, sink, cosq, sinq);
  // K+V projection (65536x1024)@(1024x512) x2, fp32-A fused cast;
  // K RoPE'd, V transposed
  gemm_proj<1><<<4096, 256, 0, stream>>>(ctx, Wkt, Wvt, kb, vtg,
                                         cosk, sink, cosq, sinq);

  attn_kernel<<<2048, 256, 0, stream>>>(qb, kb, vtg, nk, nv, obuf);

  // Output: (16384x512)@(512x1024) + bias, shifted rows
  gemm_out<<<1024, 256, 0, stream>>>(obuf, Wot, bo, out);
}